// Round 20
// baseline (207.003 us; speedup 1.0000x reference)
//
#include <hip/hip_runtime.h>
#include <hip/hip_bf16.h>

typedef _Float16 half8 __attribute__((ext_vector_type(8)));
typedef _Float16 half4 __attribute__((ext_vector_type(4)));
typedef float floatx4 __attribute__((ext_vector_type(4)));

#define HEADS_ 20
#define B_    4
#define S_    4096
#define DM    1280
#define DC    768
#define TTOK  77
#define NST   4
#define EROWS 81
#define MROWS 324
#define NT_K  20   // 1280 / 64 K-tiles

__device__ inline void gload_lds16(const void* g, void* l) {
  __builtin_amdgcn_global_load_lds((const __attribute__((address_space(1))) void*)g,
                                   (__attribute__((address_space(3))) void*)l, 16, 0, 0);
}

// ---------------- cast fp32 -> fp16 (vectorized, grid-stride) ----------------
__global__ __launch_bounds__(256) void cast_f16(const float* __restrict__ in,
                                                _Float16* __restrict__ out, long n) {
  long i = ((long)blockIdx.x * 256 + threadIdx.x) * 8L;
  long stride = (long)gridDim.x * 256 * 8;
  for (; i < n; i += stride) {
    float4 a = *(const float4*)(in + i);
    float4 b = *(const float4*)(in + i + 4);
    half8 h;
    h[0] = (_Float16)a.x; h[1] = (_Float16)a.y; h[2] = (_Float16)a.z; h[3] = (_Float16)a.w;
    h[4] = (_Float16)b.x; h[5] = (_Float16)b.y; h[6] = (_Float16)b.z; h[7] = (_Float16)b.w;
    *(half8*)(out + i) = h;
  }
}

// -------- batched transpose + cast: 6 weight mats (R,1280) f32 -> (1280,R) f16
struct TParams { const float* in[6]; _Float16* out[6]; int R[6]; };

__global__ __launch_bounds__(256) void transpose_cast6(TParams p) {
  const int z = blockIdx.z;
  const int R = p.R[z];
  const int r0 = blockIdx.y * 32, c0 = blockIdx.x * 32;
  if (r0 >= R) return;
  const float* __restrict__ in = p.in[z];
  _Float16* __restrict__ out = p.out[z];
  __shared__ float t[32][33];
  int tx = threadIdx.x & 31, ty = threadIdx.x >> 5;
  #pragma unroll
  for (int j = 0; j < 32; j += 8)
    t[ty + j][tx] = in[(size_t)(r0 + ty + j) * DM + c0 + tx];
  __syncthreads();
  #pragma unroll
  for (int j = 0; j < 32; j += 8)
    out[(size_t)(c0 + ty + j) * R + r0 + tx] = (_Float16)t[tx][ty + j];
}

// ---------------- small fp16 MFMA GEMM (KV projections, M=324) ---------------
struct Ptrs4 { const _Float16* B[4]; _Float16* C[4]; };

__global__ __launch_bounds__(256) void gemm_kv(const _Float16* __restrict__ A,
                                               Ptrs4 p4, int M, int K, int N) {
  const int tid = threadIdx.x, lane = tid & 63, w = tid >> 6;
  const _Float16* Bp = p4.B[blockIdx.z];
  _Float16* Ch = p4.C[blockIdx.z];
  const int bm = blockIdx.x, bn = blockIdx.y;

  __shared__ _Float16 As[128 * 32];
  __shared__ _Float16 Bs[128 * 32];

  const int wr = (w >> 1) * 64, wc = (w & 1) * 64;
  const int arow = wr + (lane & 15), brow = wc + (lane & 15);
  const int koff = (lane >> 4) * 8;
  floatx4 acc[4][4] = {};

  const int nk = K >> 5;
  for (int kt = 0; kt < nk; ++kt) {
    #pragma unroll
    for (int c = 0; c < 2; ++c) {
      int l16 = w * 64 + lane + c * 256;
      int row = l16 >> 2, kc = (l16 & 3) << 3;
      int gr = bm * 128 + row; if (gr > M - 1) gr = M - 1;
      gload_lds16(A + (size_t)gr * K + kt * 32 + kc, &As[(w + c * 4) * 512]);
      int grb = bn * 128 + row;
      gload_lds16(Bp + (size_t)grb * K + kt * 32 + kc, &Bs[(w + c * 4) * 512]);
    }
    __syncthreads();
    half8 af[4], bf[4];
    #pragma unroll
    for (int m = 0; m < 4; m++) af[m] = *(const half8*)&As[(arow + m * 16) * 32 + koff];
    #pragma unroll
    for (int n = 0; n < 4; n++) bf[n] = *(const half8*)&Bs[(brow + n * 16) * 32 + koff];
    #pragma unroll
    for (int m = 0; m < 4; m++)
      #pragma unroll
      for (int n = 0; n < 4; n++)
        acc[m][n] = __builtin_amdgcn_mfma_f32_16x16x32_f16(af[m], bf[n], acc[m][n], 0, 0, 0);
    __syncthreads();
  }

  const int r0 = (lane >> 4) * 4, c0 = lane & 15;
  #pragma unroll
  for (int m = 0; m < 4; m++) {
    #pragma unroll
    for (int r = 0; r < 4; r++) {
      int grow = bm * 128 + wr + m * 16 + r0 + r;
      if (grow >= M) continue;
      size_t base = (size_t)grow * N + bn * 128 + wc + c0;
      #pragma unroll
      for (int n = 0; n < 4; n++) Ch[base + n * 16] = (_Float16)acc[m][n][r];
    }
  }
}

// ---------------- 128x160 fp16 MFMA GEMM, 2 blocks/CU (round-19 proven) ------
// 55us, MfmaUtil 42-43%. aF/aG + bF/bG full double-buffering, vmcnt(9)
// all-loads-at-rendezvous, bm-major XCD swizzle, 2 blocks/CU overlap.
template<int OMODE>
__global__ __launch_bounds__(256, 2)
void gemm8(const _Float16* __restrict__ A,
           const _Float16* __restrict__ B,
           void* __restrict__ Cout,
           const float* __restrict__ bias) {
  __shared__ _Float16 lds[36864];
  _Float16* const A0 = lds;              // 8192 f16
  _Float16* const A1 = lds + 8192;
  _Float16* const B0 = lds + 16384;      // 10240 f16
  _Float16* const B1 = lds + 26624;

  const int tid = threadIdx.x, lane = tid & 63, w = tid >> 6;
  const int swz = (blockIdx.x & 7) * 128 + (blockIdx.x >> 3);
  const int bm = swz >> 3, bn = swz & 7;

  const int wr = w >> 1, wc = w & 1;           // 2M x 2N waves
  const int ql = lane & 15, lg = lane >> 4, xr = ql & 7;
  const int Abase = (wr * 64 + ql) * 64;
  const int Bbase = (wc * 80 + ql) * 64;

  const int srow = tid >> 3, sslot = tid & 7;
  const int scol = ((sslot ^ (srow & 7)) << 3);
  const _Float16* const Asrc = A + (size_t)(bm * 128 + srow) * DM + scol;
  const _Float16* const Bsrc = B + (size_t)(bn * 160 + srow) * DM + scol;
  const int ldst = w * 512;

  auto stage = [&](const _Float16* src, _Float16* buf, int q, int kt) {
    gload_lds16(src + (size_t)q * 32 * DM + kt * 64, buf + q * 2048 + ldst);
  };
  auto rdA = [&](const _Float16* buf, int m, int ks) -> half8 {
    return *(const half8*)(buf + Abase + m * 1024 + (((ks * 4 + lg) ^ xr) << 3));
  };
  auto rdB = [&](const _Float16* buf, int n, int ks) -> half8 {
    return *(const half8*)(buf + Bbase + n * 1024 + (((ks * 4 + lg) ^ xr) << 3));
  };

  floatx4 acc[4][5] = {};
  half8 bF[5], bG[5], aF[4], aG[4];

  #pragma unroll
  for (int q = 0; q < 4; ++q) stage(Asrc, A0, q, 0);
  #pragma unroll
  for (int q = 0; q < 5; ++q) stage(Bsrc, B0, q, 0);

  auto tile_body = [&](const _Float16* Ac, const _Float16* Bc,
                       _Float16* An, _Float16* Bn, int j, bool pref) {
    if (pref) {
      #pragma unroll
      for (int q = 0; q < 4; ++q) stage(Asrc, An, q, j + 1);
      #pragma unroll
      for (int q = 0; q < 5; ++q) stage(Bsrc, Bn, q, j + 1);
      asm volatile("s_waitcnt vmcnt(9)" ::: "memory");
    } else {
      asm volatile("s_waitcnt vmcnt(0)" ::: "memory");
    }
    asm volatile("s_waitcnt lgkmcnt(0)" ::: "memory");
    __builtin_amdgcn_sched_barrier(0);
    __builtin_amdgcn_s_barrier();
    __builtin_amdgcn_sched_barrier(0);

    #pragma unroll
    for (int n = 0; n < 5; ++n) bF[n] = rdB(Bc, n, 0);
    #pragma unroll
    for (int m = 0; m < 4; ++m) aF[m] = rdA(Ac, m, 0);
    #pragma unroll
    for (int m = 0; m < 4; ++m) {
      if (m == 0) { aG[0] = rdA(Ac, 0, 1); aG[1] = rdA(Ac, 1, 1); }
      if (m == 1) { aG[2] = rdA(Ac, 2, 1); aG[3] = rdA(Ac, 3, 1); bG[0] = rdB(Bc, 0, 1); }
      if (m == 2) { bG[1] = rdB(Bc, 1, 1); bG[2] = rdB(Bc, 2, 1); }
      if (m == 3) { bG[3] = rdB(Bc, 3, 1); bG[4] = rdB(Bc, 4, 1); }
      __builtin_amdgcn_s_setprio(1);
      #pragma unroll
      for (int n = 0; n < 5; ++n)
        acc[m][n] = __builtin_amdgcn_mfma_f32_16x16x32_f16(aF[m], bF[n], acc[m][n], 0, 0, 0);
      __builtin_amdgcn_s_setprio(0);
    }
    #pragma unroll
    for (int m = 0; m < 4; ++m) {
      __builtin_amdgcn_s_setprio(1);
      #pragma unroll
      for (int n = 0; n < 5; ++n)
        acc[m][n] = __builtin_amdgcn_mfma_f32_16x16x32_f16(aG[m], bG[n], acc[m][n], 0, 0, 0);
      __builtin_amdgcn_s_setprio(0);
    }
  };

  for (int j = 0; j < NT_K; j += 2) {
    tile_body(A0, B0, A1, B1, j, true);
    tile_body(A1, B1, A0, B0, j + 1, j + 2 < NT_K);
  }

  const int r0 = lg * 4;
  if constexpr (OMODE == 1) {
    _Float16* Ch = (_Float16*)Cout;
    #pragma unroll
    for (int m = 0; m < 4; ++m)
      #pragma unroll
      for (int r = 0; r < 4; ++r) {
        size_t base = (size_t)(bm * 128 + wr * 64 + m * 16 + r0 + r) * DM + bn * 160 + wc * 80 + ql;
        #pragma unroll
        for (int n = 0; n < 5; ++n)
          Ch[base + n * 16] = (_Float16)(acc[m][n][r] * 0.125f);
      }
  } else {
    float* Cf = (float*)Cout;
    float bv[5];
    #pragma unroll
    for (int n = 0; n < 5; ++n) bv[n] = bias[bn * 160 + wc * 80 + n * 16 + ql];
    #pragma unroll
    for (int m = 0; m < 4; ++m)
      #pragma unroll
      for (int r = 0; r < 4; ++r) {
        size_t base = (size_t)(bm * 128 + wr * 64 + m * 16 + r0 + r) * DM + bn * 160 + wc * 80 + ql;
        #pragma unroll
        for (int n = 0; n < 5; ++n)
          Cf[base + n * 16] = acc[m][n][r] + bv[n];
      }
  }
}

// ---------------- MFMA attention, MERGED even+odd (runtime parity) -----------
// Round-12 math verbatim; ODD template -> runtime branch so all 4 batches run
// in ONE launch (grid z=4). Removes the even->odd launch-boundary tail drain;
// scheduler co-packs short even blocks with 2x-work odd blocks. LDS worst-case
// 50KB -> 3 blocks/CU.
__global__ __launch_bounds__(256) void attn_kernel(const _Float16* __restrict__ Q,
                                                   const _Float16* __restrict__ kf,
                                                   const _Float16* __restrict__ vf,
                                                   const _Float16* __restrict__ ipk,
                                                   const _Float16* __restrict__ ipv,
                                                   _Float16* __restrict__ hid) {
  const int tid = threadIdx.x;
  const int h = blockIdx.y;
  const int b = blockIdx.z;
  const bool odd = (b & 1);
  const int hoff = h * 64;
  const int lane = tid & 63, w = tid >> 6;
  const int g = lane >> 4, ql = lane & 15;

  __shared__ _Float16 K1s[96 * 64];
  __shared__ _Float16 K2s[96 * 64];
  __shared__ _Float16 VTs[64 * 104];
  __shared__ char Pl[4][16 * 208];
  char* const K1c = (char*)K1s;
  char* const K2c = (char*)K2s;
  char* const VTc = (char*)VTs;
  char* const Pwc = Pl[w];

  const half8 zero8 = {};
  for (int i = tid; i < 96 * 8; i += 256) {
    int key = i >> 3, hb = i & 7;
    int dst = (key * 128 + hb * 16) ^ ((key & 7) << 4);
    half8 v = zero8;
    if (key < TTOK)
      v = *(const half8*)(kf + (size_t)(b * EROWS + key) * DM + hoff + hb * 8);
    else if (odd && key >= 80 && key < 84)
      v = *(const half8*)(ipk + (size_t)(b * EROWS + key - 3) * DM + hoff + hb * 8);
    *(half8*)(K1c + dst) = v;
    if (odd) {
      half8 v2 = zero8;
      if (key < TTOK)
        v2 = *(const half8*)(kf + (size_t)((b - 1) * EROWS + key) * DM + hoff + hb * 8);
      else if (key >= 80 && key < 84)
        v2 = *(const half8*)(ipk + (size_t)((b - 1) * EROWS + key - 3) * DM + hoff + hb * 8);
      *(half8*)(K2c + dst) = v2;
    }
  }
  // V staging: coalesced half8 loads, scatter to VT[d][key] (stride 104)
  for (int i = tid; i < 96 * 8; i += 256) {
    int key = i >> 3, hb = i & 7;
    half8 v = zero8;
    if (key < TTOK)
      v = *(const half8*)(vf + (size_t)(b * EROWS + key) * DM + hoff + hb * 8);
    else if (odd && key >= 80 && key < 84)
      v = *(const half8*)(ipv + (size_t)(b * EROWS + key - 3) * DM + hoff + hb * 8);
    #pragma unroll
    for (int e = 0; e < 8; ++e) VTs[(hb * 8 + e) * 104 + key] = v[e];
  }
  __syncthreads();

  for (int t = 0; t < 4; ++t) {
    const int tq0 = blockIdx.x * 256 + t * 64 + w * 16;

    const _Float16* qp = Q + (size_t)(b * S_ + tq0 + ql) * DM + hoff + g * 8;
    half8 bq0 = *(const half8*)(qp);
    half8 bq1 = *(const half8*)(qp + 32);
    half8 bq20 = zero8, bq21 = zero8;
    if (odd) {
      const _Float16* qp2 = Q + (size_t)((b - 1) * S_ + tq0 + ql) * DM + hoff + g * 8;
      bq20 = *(const half8*)(qp2);
      bq21 = *(const half8*)(qp2 + 32);
    }

    floatx4 sA[6], sB[6];
    const int nfa = odd ? 6 : 5;
    #pragma unroll 6
    for (int f = 0; f < nfa; ++f) {
      int key = f * 16 + ql;
      int sw = (key & 7) << 4;
      half8 a0 = *(const half8*)(K1c + ((key * 128 + g * 16) ^ sw));
      half8 a1 = *(const half8*)(K1c + ((key * 128 + g * 16 + 64) ^ sw));
      floatx4 z = {};
      sA[f] = __builtin_amdgcn_mfma_f32_16x16x32_f16(a0, bq0, z, 0, 0, 0);
      sA[f] = __builtin_amdgcn_mfma_f32_16x16x32_f16(a1, bq1, sA[f], 0, 0, 0);
    }
    if (odd) {
      #pragma unroll
      for (int f = 0; f < 6; ++f) {
        int key = f * 16 + ql;
        int sw = (key & 7) << 4;
        half8 a0 = *(const half8*)(K2c + ((key * 128 + g * 16) ^ sw));
        half8 a1 = *(const half8*)(K2c + ((key * 128 + g * 16 + 64) ^ sw));
        floatx4 z = {};
        sB[f] = __builtin_amdgcn_mfma_f32_16x16x32_f16(a0, bq20, z, 0, 0, 0);
        sB[f] = __builtin_amdgcn_mfma_f32_16x16x32_f16(a1, bq21, sB[f], 0, 0, 0);
      }
    }

    const int kb = g * 4;
    float mA = -1e30f;
    #pragma unroll
    for (int f = 0; f < 4; ++f)
      #pragma unroll
      for (int r = 0; r < 4; ++r) mA = fmaxf(mA, sA[f][r]);
    #pragma unroll
    for (int r = 0; r < 4; ++r) if (kb + r <= 12) mA = fmaxf(mA, sA[4][r]);
    mA = fmaxf(mA, __shfl_xor(mA, 16));
    mA = fmaxf(mA, __shfl_xor(mA, 32));
    float lA = 0.f;
    #pragma unroll
    for (int f = 0; f < 4; ++f)
      #pragma unroll
      for (int r = 0; r < 4; ++r) { float e = __expf(sA[f][r] - mA); sA[f][r] = e; lA += e; }
    #pragma unroll
    for (int r = 0; r < 4; ++r) {
      float e = (kb + r <= 12) ? __expf(sA[4][r] - mA) : 0.f;
      sA[4][r] = e; lA += e;
    }
    lA += __shfl_xor(lA, 16);
    lA += __shfl_xor(lA, 32);

    float mB = -1e30f, lB = 0.f, invB = 0.f, invIpA = 0.f, invIpB = 0.f;
    if (odd) {
      #pragma unroll
      for (int f = 0; f < 4; ++f)
        #pragma unroll
        for (int r = 0; r < 4; ++r) mB = fmaxf(mB, sB[f][r]);
      #pragma unroll
      for (int r = 0; r < 4; ++r) if (kb + r <= 12) mB = fmaxf(mB, sB[4][r]);
      mB = fmaxf(mB, __shfl_xor(mB, 16));
      mB = fmaxf(mB, __shfl_xor(mB, 32));
      #pragma unroll
      for (int f = 0; f < 4; ++f)
        #pragma unroll
        for (int r = 0; r < 4; ++r) { float e = __expf(sB[f][r] - mB); sB[f][r] = e; lB += e; }
      #pragma unroll
      for (int r = 0; r < 4; ++r) {
        float e = (kb + r <= 12) ? __expf(sB[4][r] - mB) : 0.f;
        sB[4][r] = e; lB += e;
      }
      lB += __shfl_xor(lB, 16);
      lB += __shfl_xor(lB, 32);
      invB = 0.5f / lB;

      float mia = fmaxf(fmaxf(sA[5][0], sA[5][1]), fmaxf(sA[5][2], sA[5][3]));
      float mib = fmaxf(fmaxf(sB[5][0], sB[5][1]), fmaxf(sB[5][2], sB[5][3]));
      float lia = 0.f, lib = 0.f;
      #pragma unroll
      for (int r = 0; r < 4; ++r) {
        float ea = __expf(sA[5][r] - mia); sA[5][r] = ea; lia += ea;
        float eb = __expf(sB[5][r] - mib); sB[5][r] = eb; lib += eb;
      }
      invIpA = 0.5f / lia;
      invIpB = 0.5f / lib;
    }
    const float invA = (odd ? 0.5f : 1.0f) / lA;

    asm volatile("s_waitcnt lgkmcnt(0)" ::: "memory");
    __builtin_amdgcn_sched_barrier(0);
    #pragma unroll
    for (int f = 0; f < 6; ++f) {
      #pragma unroll
      for (int r = 0; r < 4; ++r) {
        int key = f * 16 + g * 4 + r;
        float p;
        if (f < 5) p = odd ? (sA[f][r] * invA + sB[f][r] * invB) : (sA[f][r] * invA);
        else p = (odd && g == 0) ? (sA[5][r] * invIpA + sB[5][r] * invIpB) : 0.f;
        *(_Float16*)(Pwc + ql * 208 + key * 2) = (_Float16)p;
      }
    }
    asm volatile("s_waitcnt lgkmcnt(0)" ::: "memory");
    __builtin_amdgcn_sched_barrier(0);

    half8 pf[3];
    #pragma unroll
    for (int kf2 = 0; kf2 < 3; ++kf2)
      pf[kf2] = *(const half8*)(Pwc + ql * 208 + g * 16 + kf2 * 64);
    floatx4 acc_o[4] = {};
    #pragma unroll
    for (int dt = 0; dt < 4; ++dt)
      #pragma unroll
      for (int kf2 = 0; kf2 < 3; ++kf2) {
        half8 vfr = *(const half8*)(VTc + (dt * 16 + ql) * 208 + g * 16 + kf2 * 64);
        acc_o[dt] = __builtin_amdgcn_mfma_f32_16x16x32_f16(vfr, pf[kf2], acc_o[dt], 0, 0, 0);
      }

    _Float16* hr = hid + (size_t)(b * S_ + tq0 + ql) * DM + hoff;
    #pragma unroll
    for (int dt = 0; dt < 4; ++dt) {
      half4 hv;
      #pragma unroll
      for (int r = 0; r < 4; ++r) hv[r] = (_Float16)acc_o[dt][r];
      *(half4*)(hr + dt * 16 + g * 4) = hv;
    }
  }
}

// -----------------------------------------------------------------------------
extern "C" void kernel_launch(void* const* d_in, const int* in_sizes, int n_in,
                              void* d_out, int out_size, void* d_ws, size_t ws_size,
                              hipStream_t stream) {
  const float* hs   = (const float*)d_in[0];
  const float* ehs  = (const float*)d_in[1];
  const float* Wq   = (const float*)d_in[2];
  const float* Wk   = (const float*)d_in[3];
  const float* Wv   = (const float*)d_in[4];
  const float* Wkip = (const float*)d_in[5];
  const float* Wvip = (const float*)d_in[6];
  const float* Wo   = (const float*)d_in[7];
  const float* bo   = (const float*)d_in[8];
  float* out = (float*)d_out;

  char* ws = (char*)d_ws;
  size_t off = 0;
  auto alloc = [&](size_t bytes) {
    void* p = ws + off;
    off += (bytes + 255) & ~(size_t)255;
    return p;
  };
  _Float16* hs16   = (_Float16*)alloc(20971520UL * 2);  // reused later as hid
  _Float16* ehs16  = (_Float16*)alloc(248832UL * 2);
  _Float16* WqT    = (_Float16*)alloc(1638400UL * 2);
  _Float16* WoT    = (_Float16*)alloc(1638400UL * 2);
  _Float16* WkT    = (_Float16*)alloc(983040UL * 2);
  _Float16* WvT    = (_Float16*)alloc(983040UL * 2);
  _Float16* WkipT  = (_Float16*)alloc(983040UL * 2);
  _Float16* WvipT  = (_Float16*)alloc(983040UL * 2);
  _Float16* Q16    = (_Float16*)alloc(20971520UL * 2);
  _Float16* kf16   = (_Float16*)alloc(324UL * 1280 * 2);
  _Float16* vf16   = (_Float16*)alloc(324UL * 1280 * 2);
  _Float16* ipkf16 = (_Float16*)alloc(324UL * 1280 * 2);
  _Float16* ipvf16 = (_Float16*)alloc(324UL * 1280 * 2);
  _Float16* hid16 = hs16;  // safe reuse: attn runs after gemm-Q consumed hs16

  cast_f16<<<2048, 256, 0, stream>>>(hs, hs16, 20971520L);
  cast_f16<<<128, 256, 0, stream>>>(ehs, ehs16, 248832L);

  TParams tp;
  tp.in[0] = Wq;   tp.out[0] = WqT;   tp.R[0] = 1280;
  tp.in[1] = Wo;   tp.out[1] = WoT;   tp.R[1] = 1280;
  tp.in[2] = Wk;   tp.out[2] = WkT;   tp.R[2] = 768;
  tp.in[3] = Wv;   tp.out[3] = WvT;   tp.R[3] = 768;
  tp.in[4] = Wkip; tp.out[4] = WkipT; tp.R[4] = 768;
  tp.in[5] = Wvip; tp.out[5] = WvipT; tp.R[5] = 768;
  transpose_cast6<<<dim3(40, 40, 6), 256, 0, stream>>>(tp);

  Ptrs4 p4;
  p4.B[0] = WkT; p4.B[1] = WvT; p4.B[2] = WkipT; p4.B[3] = WvipT;
  p4.C[0] = kf16; p4.C[1] = vf16; p4.C[2] = ipkf16; p4.C[3] = ipvf16;

  gemm_kv<<<dim3(3, 10, 4), 256, 0, stream>>>(ehs16, p4, MROWS, DC, DM);
  gemm8<1><<<1024, 256, 0, stream>>>(hs16, WqT, (void*)Q16, nullptr);
  attn_kernel<<<dim3(16, 20, 4), 256, 0, stream>>>(Q16, kf16, vf16, ipkf16, ipvf16, hid16);
  gemm8<2><<<1024, 256, 0, stream>>>(hid16, WoT, (void*)out, bo);
}

// Round 21
// 206.760 us; speedup vs baseline: 1.0012x; 1.0012x over previous
//
#include <hip/hip_runtime.h>
#include <hip/hip_bf16.h>

typedef _Float16 half8 __attribute__((ext_vector_type(8)));
typedef _Float16 half4 __attribute__((ext_vector_type(4)));
typedef float floatx4 __attribute__((ext_vector_type(4)));

#define HEADS_ 20
#define B_    4
#define S_    4096
#define DM    1280
#define DC    768
#define TTOK  77
#define NST   4
#define EROWS 81
#define MROWS 324
#define NT_K  20   // 1280 / 64 K-tiles

__device__ inline void gload_lds16(const void* g, void* l) {
  __builtin_amdgcn_global_load_lds((const __attribute__((address_space(1))) void*)g,
                                   (__attribute__((address_space(3))) void*)l, 16, 0, 0);
}

// ---------------- cast fp32 -> fp16 (vectorized, grid-stride) ----------------
__global__ __launch_bounds__(256) void cast_f16(const float* __restrict__ in,
                                                _Float16* __restrict__ out, long n) {
  long i = ((long)blockIdx.x * 256 + threadIdx.x) * 8L;
  long stride = (long)gridDim.x * 256 * 8;
  for (; i < n; i += stride) {
    float4 a = *(const float4*)(in + i);
    float4 b = *(const float4*)(in + i + 4);
    half8 h;
    h[0] = (_Float16)a.x; h[1] = (_Float16)a.y; h[2] = (_Float16)a.z; h[3] = (_Float16)a.w;
    h[4] = (_Float16)b.x; h[5] = (_Float16)b.y; h[6] = (_Float16)b.z; h[7] = (_Float16)b.w;
    *(half8*)(out + i) = h;
  }
}

// -------- batched transpose + cast: 6 weight mats (R,1280) f32 -> (1280,R) f16
struct TParams { const float* in[6]; _Float16* out[6]; int R[6]; };

__global__ __launch_bounds__(256) void transpose_cast6(TParams p) {
  const int z = blockIdx.z;
  const int R = p.R[z];
  const int r0 = blockIdx.y * 32, c0 = blockIdx.x * 32;
  if (r0 >= R) return;
  const float* __restrict__ in = p.in[z];
  _Float16* __restrict__ out = p.out[z];
  __shared__ float t[32][33];
  int tx = threadIdx.x & 31, ty = threadIdx.x >> 5;
  #pragma unroll
  for (int j = 0; j < 32; j += 8)
    t[ty + j][tx] = in[(size_t)(r0 + ty + j) * DM + c0 + tx];
  __syncthreads();
  #pragma unroll
  for (int j = 0; j < 32; j += 8)
    out[(size_t)(c0 + ty + j) * R + r0 + tx] = (_Float16)t[tx][ty + j];
}

// ---------------- small fp16 MFMA GEMM (KV projections, M=324) ---------------
struct Ptrs4 { const _Float16* B[4]; _Float16* C[4]; };

__global__ __launch_bounds__(256) void gemm_kv(const _Float16* __restrict__ A,
                                               Ptrs4 p4, int M, int K, int N) {
  const int tid = threadIdx.x, lane = tid & 63, w = tid >> 6;
  const _Float16* Bp = p4.B[blockIdx.z];
  _Float16* Ch = p4.C[blockIdx.z];
  const int bm = blockIdx.x, bn = blockIdx.y;

  __shared__ _Float16 As[128 * 32];
  __shared__ _Float16 Bs[128 * 32];

  const int wr = (w >> 1) * 64, wc = (w & 1) * 64;
  const int arow = wr + (lane & 15), brow = wc + (lane & 15);
  const int koff = (lane >> 4) * 8;
  floatx4 acc[4][4] = {};

  const int nk = K >> 5;
  for (int kt = 0; kt < nk; ++kt) {
    #pragma unroll
    for (int c = 0; c < 2; ++c) {
      int l16 = w * 64 + lane + c * 256;
      int row = l16 >> 2, kc = (l16 & 3) << 3;
      int gr = bm * 128 + row; if (gr > M - 1) gr = M - 1;
      gload_lds16(A + (size_t)gr * K + kt * 32 + kc, &As[(w + c * 4) * 512]);
      int grb = bn * 128 + row;
      gload_lds16(Bp + (size_t)grb * K + kt * 32 + kc, &Bs[(w + c * 4) * 512]);
    }
    __syncthreads();
    half8 af[4], bf[4];
    #pragma unroll
    for (int m = 0; m < 4; m++) af[m] = *(const half8*)&As[(arow + m * 16) * 32 + koff];
    #pragma unroll
    for (int n = 0; n < 4; n++) bf[n] = *(const half8*)&Bs[(brow + n * 16) * 32 + koff];
    #pragma unroll
    for (int m = 0; m < 4; m++)
      #pragma unroll
      for (int n = 0; n < 4; n++)
        acc[m][n] = __builtin_amdgcn_mfma_f32_16x16x32_f16(af[m], bf[n], acc[m][n], 0, 0, 0);
    __syncthreads();
  }

  const int r0 = (lane >> 4) * 4, c0 = lane & 15;
  #pragma unroll
  for (int m = 0; m < 4; m++) {
    #pragma unroll
    for (int r = 0; r < 4; r++) {
      int grow = bm * 128 + wr + m * 16 + r0 + r;
      if (grow >= M) continue;
      size_t base = (size_t)grow * N + bn * 128 + wc + c0;
      #pragma unroll
      for (int n = 0; n < 4; n++) Ch[base + n * 16] = (_Float16)acc[m][n][r];
    }
  }
}

// ---------------- 128x160 fp16 MFMA GEMM, 2 blocks/CU (round-19 proven) ------
template<int OMODE>
__global__ __launch_bounds__(256, 2)
void gemm8(const _Float16* __restrict__ A,
           const _Float16* __restrict__ B,
           void* __restrict__ Cout,
           const float* __restrict__ bias) {
  __shared__ _Float16 lds[36864];
  _Float16* const A0 = lds;
  _Float16* const A1 = lds + 8192;
  _Float16* const B0 = lds + 16384;
  _Float16* const B1 = lds + 26624;

  const int tid = threadIdx.x, lane = tid & 63, w = tid >> 6;
  const int swz = (blockIdx.x & 7) * 128 + (blockIdx.x >> 3);
  const int bm = swz >> 3, bn = swz & 7;

  const int wr = w >> 1, wc = w & 1;
  const int ql = lane & 15, lg = lane >> 4, xr = ql & 7;
  const int Abase = (wr * 64 + ql) * 64;
  const int Bbase = (wc * 80 + ql) * 64;

  const int srow = tid >> 3, sslot = tid & 7;
  const int scol = ((sslot ^ (srow & 7)) << 3);
  const _Float16* const Asrc = A + (size_t)(bm * 128 + srow) * DM + scol;
  const _Float16* const Bsrc = B + (size_t)(bn * 160 + srow) * DM + scol;
  const int ldst = w * 512;

  auto stage = [&](const _Float16* src, _Float16* buf, int q, int kt) {
    gload_lds16(src + (size_t)q * 32 * DM + kt * 64, buf + q * 2048 + ldst);
  };
  auto rdA = [&](const _Float16* buf, int m, int ks) -> half8 {
    return *(const half8*)(buf + Abase + m * 1024 + (((ks * 4 + lg) ^ xr) << 3));
  };
  auto rdB = [&](const _Float16* buf, int n, int ks) -> half8 {
    return *(const half8*)(buf + Bbase + n * 1024 + (((ks * 4 + lg) ^ xr) << 3));
  };

  floatx4 acc[4][5] = {};
  half8 bF[5], bG[5], aF[4], aG[4];

  #pragma unroll
  for (int q = 0; q < 4; ++q) stage(Asrc, A0, q, 0);
  #pragma unroll
  for (int q = 0; q < 5; ++q) stage(Bsrc, B0, q, 0);

  auto tile_body = [&](const _Float16* Ac, const _Float16* Bc,
                       _Float16* An, _Float16* Bn, int j, bool pref) {
    if (pref) {
      #pragma unroll
      for (int q = 0; q < 4; ++q) stage(Asrc, An, q, j + 1);
      #pragma unroll
      for (int q = 0; q < 5; ++q) stage(Bsrc, Bn, q, j + 1);
      asm volatile("s_waitcnt vmcnt(9)" ::: "memory");
    } else {
      asm volatile("s_waitcnt vmcnt(0)" ::: "memory");
    }
    asm volatile("s_waitcnt lgkmcnt(0)" ::: "memory");
    __builtin_amdgcn_sched_barrier(0);
    __builtin_amdgcn_s_barrier();
    __builtin_amdgcn_sched_barrier(0);

    #pragma unroll
    for (int n = 0; n < 5; ++n) bF[n] = rdB(Bc, n, 0);
    #pragma unroll
    for (int m = 0; m < 4; ++m) aF[m] = rdA(Ac, m, 0);
    #pragma unroll
    for (int m = 0; m < 4; ++m) {
      if (m == 0) { aG[0] = rdA(Ac, 0, 1); aG[1] = rdA(Ac, 1, 1); }
      if (m == 1) { aG[2] = rdA(Ac, 2, 1); aG[3] = rdA(Ac, 3, 1); bG[0] = rdB(Bc, 0, 1); }
      if (m == 2) { bG[1] = rdB(Bc, 1, 1); bG[2] = rdB(Bc, 2, 1); }
      if (m == 3) { bG[3] = rdB(Bc, 3, 1); bG[4] = rdB(Bc, 4, 1); }
      __builtin_amdgcn_s_setprio(1);
      #pragma unroll
      for (int n = 0; n < 5; ++n)
        acc[m][n] = __builtin_amdgcn_mfma_f32_16x16x32_f16(aF[m], bF[n], acc[m][n], 0, 0, 0);
      __builtin_amdgcn_s_setprio(0);
    }
    #pragma unroll
    for (int m = 0; m < 4; ++m) {
      __builtin_amdgcn_s_setprio(1);
      #pragma unroll
      for (int n = 0; n < 5; ++n)
        acc[m][n] = __builtin_amdgcn_mfma_f32_16x16x32_f16(aG[m], bG[n], acc[m][n], 0, 0, 0);
      __builtin_amdgcn_s_setprio(0);
    }
  };

  for (int j = 0; j < NT_K; j += 2) {
    tile_body(A0, B0, A1, B1, j, true);
    tile_body(A1, B1, A0, B0, j + 1, j + 2 < NT_K);
  }

  const int r0 = lg * 4;
  if constexpr (OMODE == 1) {
    _Float16* Ch = (_Float16*)Cout;
    #pragma unroll
    for (int m = 0; m < 4; ++m)
      #pragma unroll
      for (int r = 0; r < 4; ++r) {
        size_t base = (size_t)(bm * 128 + wr * 64 + m * 16 + r0 + r) * DM + bn * 160 + wc * 80 + ql;
        #pragma unroll
        for (int n = 0; n < 5; ++n)
          Ch[base + n * 16] = (_Float16)(acc[m][n][r] * 0.125f);
      }
  } else {
    float* Cf = (float*)Cout;
    float bv[5];
    #pragma unroll
    for (int n = 0; n < 5; ++n) bv[n] = bias[bn * 160 + wc * 80 + n * 16 + ql];
    #pragma unroll
    for (int m = 0; m < 4; ++m)
      #pragma unroll
      for (int r = 0; r < 4; ++r) {
        size_t base = (size_t)(bm * 128 + wr * 64 + m * 16 + r0 + r) * DM + bn * 160 + wc * 80 + ql;
        #pragma unroll
        for (int n = 0; n < 5; ++n)
          Cf[base + n * 16] = acc[m][n][r] + bv[n];
      }
  }
}

// ---------------- MFMA attention with P-sharing --------------------------------
// EVEN (b=2z): computes own normalized P (text cols 0..79 + ip cols 80..95,
// ip normalized lane-locally at g==0), STORES P to global (for the odd pair),
// PV with V ip-rows zero (ip probs in P don't affect even output). ODD
// (b=2z+1): computes only its OWN P (no K2/q2/sB at all), loads the even
// pair's P, blends (pf+pe)*0.5 in packed f16, PV with V incl. own ip rows.
// attn<false> launch precedes attn<true> -> dependency satisfied by stream
// order. LDS ~38KB -> 4 blocks/CU for both.
template<bool ODD>
__global__ __launch_bounds__(256) void attn_kernel(const _Float16* __restrict__ Q,
                                                   const _Float16* __restrict__ kf,
                                                   const _Float16* __restrict__ vf,
                                                   const _Float16* __restrict__ ipk,
                                                   const _Float16* __restrict__ ipv,
                                                   _Float16* __restrict__ P,
                                                   _Float16* __restrict__ hid) {
  const int tid = threadIdx.x;
  const int h = blockIdx.y;
  const int pbz = blockIdx.z;
  const int b = pbz * 2 + (ODD ? 1 : 0);
  const int hoff = h * 64;
  const int lane = tid & 63, w = tid >> 6;
  const int g = lane >> 4, ql = lane & 15;

  __shared__ _Float16 K1s[96 * 64];
  __shared__ _Float16 VTs[64 * 104];
  __shared__ char Pl[4][16 * 208];
  char* const K1c = (char*)K1s;
  char* const VTc = (char*)VTs;
  char* const Pwc = Pl[w];

  const half8 zero8 = {};
  // K1: text keys 0..76 + own-b ip keys 80..83 (both parities)
  for (int i = tid; i < 96 * 8; i += 256) {
    int key = i >> 3, hb = i & 7;
    int dst = (key * 128 + hb * 16) ^ ((key & 7) << 4);
    half8 v = zero8;
    if (key < TTOK)
      v = *(const half8*)(kf + (size_t)(b * EROWS + key) * DM + hoff + hb * 8);
    else if (key >= 80 && key < 84)
      v = *(const half8*)(ipk + (size_t)(b * EROWS + key - 3) * DM + hoff + hb * 8);
    *(half8*)(K1c + dst) = v;
  }
  // V: text rows; ip rows only for ODD (even's ip P-cols then contribute 0)
  for (int i = tid; i < 96 * 8; i += 256) {
    int key = i >> 3, hb = i & 7;
    half8 v = zero8;
    if (key < TTOK)
      v = *(const half8*)(vf + (size_t)(b * EROWS + key) * DM + hoff + hb * 8);
    else if (ODD && key >= 80 && key < 84)
      v = *(const half8*)(ipv + (size_t)(b * EROWS + key - 3) * DM + hoff + hb * 8);
    #pragma unroll
    for (int e = 0; e < 8; ++e) VTs[(hb * 8 + e) * 104 + key] = v[e];
  }
  __syncthreads();

  for (int t = 0; t < 4; ++t) {
    const int tq0 = blockIdx.x * 256 + t * 64 + w * 16;

    const _Float16* qp = Q + (size_t)(b * S_ + tq0 + ql) * DM + hoff + g * 8;
    half8 bq0 = *(const half8*)(qp);
    half8 bq1 = *(const half8*)(qp + 32);

    // QK^T (swapped): 6 fragment pairs, own q / own K only
    floatx4 sA[6];
    #pragma unroll
    for (int f = 0; f < 6; ++f) {
      int key = f * 16 + ql;
      int sw = (key & 7) << 4;
      half8 a0 = *(const half8*)(K1c + ((key * 128 + g * 16) ^ sw));
      half8 a1 = *(const half8*)(K1c + ((key * 128 + g * 16 + 64) ^ sw));
      floatx4 z = {};
      sA[f] = __builtin_amdgcn_mfma_f32_16x16x32_f16(a0, bq0, z, 0, 0, 0);
      sA[f] = __builtin_amdgcn_mfma_f32_16x16x32_f16(a1, bq1, sA[f], 0, 0, 0);
    }

    // text softmax (keys 0..76, cross-lane-group) + ip softmax (g==0 lane-local)
    const int kb = g * 4;
    float mA = -1e30f;
    #pragma unroll
    for (int f = 0; f < 4; ++f)
      #pragma unroll
      for (int r = 0; r < 4; ++r) mA = fmaxf(mA, sA[f][r]);
    #pragma unroll
    for (int r = 0; r < 4; ++r) if (kb + r <= 12) mA = fmaxf(mA, sA[4][r]);
    mA = fmaxf(mA, __shfl_xor(mA, 16));
    mA = fmaxf(mA, __shfl_xor(mA, 32));
    float lA = 0.f;
    #pragma unroll
    for (int f = 0; f < 4; ++f)
      #pragma unroll
      for (int r = 0; r < 4; ++r) { float e = __expf(sA[f][r] - mA); sA[f][r] = e; lA += e; }
    #pragma unroll
    for (int r = 0; r < 4; ++r) {
      float e = (kb + r <= 12) ? __expf(sA[4][r] - mA) : 0.f;
      sA[4][r] = e; lA += e;
    }
    lA += __shfl_xor(lA, 16);
    lA += __shfl_xor(lA, 32);
    const float invA = 1.0f / lA;

    float mia = fmaxf(fmaxf(sA[5][0], sA[5][1]), fmaxf(sA[5][2], sA[5][3]));
    float lia = 0.f;
    #pragma unroll
    for (int r = 0; r < 4; ++r) { float e = __expf(sA[5][r] - mia); sA[5][r] = e; lia += e; }
    const float invIpA = 1.0f / lia;

    // write full normalized own-P to per-wave LDS [q][key]
    asm volatile("s_waitcnt lgkmcnt(0)" ::: "memory");
    __builtin_amdgcn_sched_barrier(0);
    #pragma unroll
    for (int f = 0; f < 6; ++f) {
      #pragma unroll
      for (int r = 0; r < 4; ++r) {
        int key = f * 16 + g * 4 + r;
        float p;
        if (f < 5) p = sA[f][r] * invA;
        else p = (g == 0) ? (sA[5][r] * invIpA) : 0.f;
        *(_Float16*)(Pwc + ql * 208 + key * 2) = (_Float16)p;
      }
    }
    asm volatile("s_waitcnt lgkmcnt(0)" ::: "memory");
    __builtin_amdgcn_sched_barrier(0);

    half8 pf[3];
    #pragma unroll
    for (int kf2 = 0; kf2 < 3; ++kf2)
      pf[kf2] = *(const half8*)(Pwc + ql * 208 + g * 16 + kf2 * 64);

    // P exchange: even stores, odd loads pair P and blends
    _Float16* const Pg = P + (((size_t)pbz * HEADS_ + h) * S_ + tq0 + ql) * 96 + g * 8;
    if constexpr (!ODD) {
      #pragma unroll
      for (int kf2 = 0; kf2 < 3; ++kf2)
        *(half8*)(Pg + kf2 * 32) = pf[kf2];
    } else {
      half8 pe[3];
      #pragma unroll
      for (int kf2 = 0; kf2 < 3; ++kf2) pe[kf2] = *(const half8*)(Pg + kf2 * 32);
      #pragma unroll
      for (int kf2 = 0; kf2 < 3; ++kf2)
        pf[kf2] = (pf[kf2] + pe[kf2]) * (_Float16)0.5f;
    }

    floatx4 acc_o[4] = {};
    #pragma unroll
    for (int dt = 0; dt < 4; ++dt)
      #pragma unroll
      for (int kf2 = 0; kf2 < 3; ++kf2) {
        half8 vfr = *(const half8*)(VTc + (dt * 16 + ql) * 208 + g * 16 + kf2 * 64);
        acc_o[dt] = __builtin_amdgcn_mfma_f32_16x16x32_f16(vfr, pf[kf2], acc_o[dt], 0, 0, 0);
      }

    _Float16* hr = hid + (size_t)(b * S_ + tq0 + ql) * DM + hoff;
    #pragma unroll
    for (int dt = 0; dt < 4; ++dt) {
      half4 hv;
      #pragma unroll
      for (int r = 0; r < 4; ++r) hv[r] = (_Float16)acc_o[dt][r];
      *(half4*)(hr + dt * 16 + g * 4) = hv;
    }
  }
}

// -----------------------------------------------------------------------------
extern "C" void kernel_launch(void* const* d_in, const int* in_sizes, int n_in,
                              void* d_out, int out_size, void* d_ws, size_t ws_size,
                              hipStream_t stream) {
  const float* hs   = (const float*)d_in[0];
  const float* ehs  = (const float*)d_in[1];
  const float* Wq   = (const float*)d_in[2];
  const float* Wk   = (const float*)d_in[3];
  const float* Wv   = (const float*)d_in[4];
  const float* Wkip = (const float*)d_in[5];
  const float* Wvip = (const float*)d_in[6];
  const float* Wo   = (const float*)d_in[7];
  const float* bo   = (const float*)d_in[8];
  float* out = (float*)d_out;

  char* ws = (char*)d_ws;
  size_t off = 0;
  auto alloc = [&](size_t bytes) {
    void* p = ws + off;
    off += (bytes + 255) & ~(size_t)255;
    return p;
  };
  _Float16* hs16   = (_Float16*)alloc(20971520UL * 2);  // reused later as hid
  _Float16* ehs16  = (_Float16*)alloc(248832UL * 2);
  _Float16* WqT    = (_Float16*)alloc(1638400UL * 2);
  _Float16* WoT    = (_Float16*)alloc(1638400UL * 2);
  _Float16* WkT    = (_Float16*)alloc(983040UL * 2);
  _Float16* WvT    = (_Float16*)alloc(983040UL * 2);
  _Float16* WkipT  = (_Float16*)alloc(983040UL * 2);
  _Float16* WvipT  = (_Float16*)alloc(983040UL * 2);
  _Float16* Q16    = (_Float16*)alloc(20971520UL * 2);
  _Float16* kf16   = (_Float16*)alloc(324UL * 1280 * 2);
  _Float16* vf16   = (_Float16*)alloc(324UL * 1280 * 2);
  _Float16* ipkf16 = (_Float16*)alloc(324UL * 1280 * 2);
  _Float16* ipvf16 = (_Float16*)alloc(324UL * 1280 * 2);
  _Float16* Pbuf   = (_Float16*)alloc(2UL * HEADS_ * S_ * 96 * 2);  // even-pair P
  _Float16* hid16 = hs16;  // safe reuse: attn runs after gemm-Q consumed hs16

  cast_f16<<<2048, 256, 0, stream>>>(hs, hs16, 20971520L);
  cast_f16<<<128, 256, 0, stream>>>(ehs, ehs16, 248832L);

  TParams tp;
  tp.in[0] = Wq;   tp.out[0] = WqT;   tp.R[0] = 1280;
  tp.in[1] = Wo;   tp.out[1] = WoT;   tp.R[1] = 1280;
  tp.in[2] = Wk;   tp.out[2] = WkT;   tp.R[2] = 768;
  tp.in[3] = Wv;   tp.out[3] = WvT;   tp.R[3] = 768;
  tp.in[4] = Wkip; tp.out[4] = WkipT; tp.R[4] = 768;
  tp.in[5] = Wvip; tp.out[5] = WvipT; tp.R[5] = 768;
  transpose_cast6<<<dim3(40, 40, 6), 256, 0, stream>>>(tp);

  Ptrs4 p4;
  p4.B[0] = WkT; p4.B[1] = WvT; p4.B[2] = WkipT; p4.B[3] = WvipT;
  p4.C[0] = kf16; p4.C[1] = vf16; p4.C[2] = ipkf16; p4.C[3] = ipvf16;

  gemm_kv<<<dim3(3, 10, 4), 256, 0, stream>>>(ehs16, p4, MROWS, DC, DM);
  gemm8<1><<<1024, 256, 0, stream>>>(hs16, WqT, (void*)Q16, nullptr);
  attn_kernel<false><<<dim3(16, 20, 2), 256, 0, stream>>>(Q16, kf16, vf16, ipkf16, ipvf16, Pbuf, hid16);
  attn_kernel<true><<<dim3(16, 20, 2), 256, 0, stream>>>(Q16, kf16, vf16, ipkf16, ipvf16, Pbuf, hid16);
  gemm8<2><<<1024, 256, 0, stream>>>(hid16, WoT, (void*)out, bo);
}